// Round 1
// baseline (361.506 us; speedup 1.0000x reference)
//
#include <hip/hip_runtime.h>
#include <hip/hip_bf16.h>

typedef _Float16 half8 __attribute__((ext_vector_type(8)));
typedef float floatx4 __attribute__((ext_vector_type(4)));

#define B_  16
#define S_  2048
#define D_  256
#define BM  128
#define BN  32
#define NW  8
#define NTHREADS 512
#define KT_RS 264   // 256 + 8 pad (f16 units); 528 B rows, 16B-aligned
#define VT_RS 40    // 32 + 8 pad
#define P_RS  40
#define OCH_RS 132  // 128 + 4 pad (f32 units)
#define LOG2E 1.4426950408889634f

__global__ __launch_bounds__(NTHREADS, 1)
void attn_flash_f16(const float* __restrict__ q,
                    const float* __restrict__ k,
                    const float* __restrict__ v,
                    const int*   __restrict__ mask,
                    float* __restrict__ out)
{
    // 47744 B static LDS; epilogue reuses the front as a [64][OCH_RS] f32 buffer
    __shared__ __align__(16) char smem_raw[(BN*KT_RS + D_*VT_RS + NW*16*P_RS)*2 + BN*4];
    _Float16* kt    = (_Float16*)smem_raw;            // [BN][KT_RS]  = K^T tile (j, d)
    _Float16* vt    = kt + BN*KT_RS;                  // [D_][VT_RS]  = V^T tile (d, j)
    _Float16* pbuf  = vt + D_*VT_RS;                  // [NW][16][P_RS] per-wave P strip
    float*    moffs = (float*)(pbuf + NW*16*P_RS);    // [BN] mask offsets
    float*    och   = (float*)smem_raw;               // epilogue transpose buffer

    const int tid  = threadIdx.x;
    const int w    = tid >> 6;      // wave 0..7
    const int lane = tid & 63;
    const int n15  = lane & 15;
    const int qq   = lane >> 4;     // quad 0..3

    // XCD-aware decode: each XCD gets all 16 Q-tiles of 2 batches (L2 locality)
    const int bx = blockIdx.x;
    const int x  = bx & 7;
    const int j_ = bx >> 3;
    const int b  = 2*x + (j_ >> 4);
    const int qt = j_ & 15;
    const int i0 = qt * BM;

    const float* qb = q + (size_t)b * S_ * D_;
    const float* kb = k + (size_t)b * D_ * S_;
    const float* vb = v + (size_t)b * S_ * D_;
    const int*   mb = mask + (size_t)b * S_;
    float*       ob = out + (size_t)b * D_ * S_;

    // ---- preload Q fragments (A-operand, rows i0+16w+n15), f16, kept in regs
    half8 qf[8];
    {
        const float* qrow = qb + (size_t)(i0 + 16*w + n15) * D_;
        #pragma unroll
        for (int s = 0; s < 8; ++s) {
            const float4 a = *(const float4*)(qrow + 32*s + 8*qq);
            const float4 c = *(const float4*)(qrow + 32*s + 8*qq + 4);
            half8 h;
            h[0]=(_Float16)a.x; h[1]=(_Float16)a.y; h[2]=(_Float16)a.z; h[3]=(_Float16)a.w;
            h[4]=(_Float16)c.x; h[5]=(_Float16)c.y; h[6]=(_Float16)c.z; h[7]=(_Float16)c.w;
            qf[s] = h;
        }
    }

    floatx4 o[16];
    #pragma unroll
    for (int i = 0; i < 16; ++i) o[i] = (floatx4){0.f,0.f,0.f,0.f};
    float m_r[4] = {-3.0e38f,-3.0e38f,-3.0e38f,-3.0e38f};
    float l_r[4] = {0.f,0.f,0.f,0.f};

    _Float16* pw = pbuf + w * 16 * P_RS;

    for (int t = 0; t < S_/BN; ++t) {
        const int j0 = t * BN;

        // ---- stage K tile transposed: kt[j][d] = k[b][d][j0+j]
        {
            const int jq = tid & 7;          // float4 index along j
            const int d0 = tid >> 3;         // 0..63
            #pragma unroll
            for (int r = 0; r < 4; ++r) {
                const int d = d0 + 64*r;
                const float4 kv = *(const float4*)(kb + (size_t)d * S_ + j0 + 4*jq);
                kt[(4*jq+0)*KT_RS + d] = (_Float16)kv.x;
                kt[(4*jq+1)*KT_RS + d] = (_Float16)kv.y;
                kt[(4*jq+2)*KT_RS + d] = (_Float16)kv.z;
                kt[(4*jq+3)*KT_RS + d] = (_Float16)kv.w;
            }
            // V tile transposed: vt[d][j] = v[b][j0+j][d]
            const int jv = tid & 7;
            const int dq = tid >> 3;         // float4 index along d, 0..63
            #pragma unroll
            for (int r = 0; r < 4; ++r) {
                const int j = jv + 8*r;
                const float4 vv = *(const float4*)(vb + (size_t)(j0 + j) * D_ + 4*dq);
                vt[(4*dq+0)*VT_RS + j] = (_Float16)vv.x;
                vt[(4*dq+1)*VT_RS + j] = (_Float16)vv.y;
                vt[(4*dq+2)*VT_RS + j] = (_Float16)vv.z;
                vt[(4*dq+3)*VT_RS + j] = (_Float16)vv.w;
            }
            if (tid < BN) moffs[tid] = mb[j0 + tid] ? 0.0f : -1.0e9f;
        }
        __syncthreads();

        // ---- S = Q @ K  (16x64-row strip per wave x 2 col-tiles of 16)
        floatx4 sc0 = {0.f,0.f,0.f,0.f}, sc1 = {0.f,0.f,0.f,0.f};
        #pragma unroll
        for (int s = 0; s < 8; ++s) {
            const half8 b0 = *(const half8*)(kt + (n15   )*KT_RS + 32*s + 8*qq);
            const half8 b1 = *(const half8*)(kt + (16+n15)*KT_RS + 32*s + 8*qq);
            sc0 = __builtin_amdgcn_mfma_f32_16x16x32_f16(qf[s], b0, sc0, 0,0,0);
            sc1 = __builtin_amdgcn_mfma_f32_16x16x32_f16(qf[s], b1, sc1, 0,0,0);
        }

        // ---- mask + online softmax (C layout: row = 4*qq+r, col = 16c+n15)
        const float mo0 = moffs[n15], mo1 = moffs[16+n15];
        float sv0[4], sv1[4], mx[4];
        #pragma unroll
        for (int r = 0; r < 4; ++r) {
            sv0[r] = sc0[r] + mo0;
            sv1[r] = sc1[r] + mo1;
            mx[r]  = fmaxf(sv0[r], sv1[r]);
        }
        #pragma unroll
        for (int off = 1; off <= 8; off <<= 1) {
            #pragma unroll
            for (int r = 0; r < 4; ++r) mx[r] = fmaxf(mx[r], __shfl_xor(mx[r], off, 64));
        }
        float alpha[4], p0[4], p1[4], rs[4];
        #pragma unroll
        for (int r = 0; r < 4; ++r) {
            const float mn = fmaxf(m_r[r], mx[r]);
            alpha[r] = __builtin_amdgcn_exp2f((m_r[r] - mn) * LOG2E);
            m_r[r]   = mn;
            p0[r] = __builtin_amdgcn_exp2f((sv0[r] - mn) * LOG2E);
            p1[r] = __builtin_amdgcn_exp2f((sv1[r] - mn) * LOG2E);
            rs[r] = p0[r] + p1[r];
        }
        #pragma unroll
        for (int off = 1; off <= 8; off <<= 1) {
            #pragma unroll
            for (int r = 0; r < 4; ++r) rs[r] += __shfl_xor(rs[r], off, 64);
        }
        #pragma unroll
        for (int r = 0; r < 4; ++r) l_r[r] = l_r[r]*alpha[r] + rs[r];

        // ---- P (C layout) -> LDS -> A layout; rescale O; O += P @ V
        #pragma unroll
        for (int r = 0; r < 4; ++r) {
            pw[(qq*4+r)*P_RS + n15     ] = (_Float16)p0[r];
            pw[(qq*4+r)*P_RS + 16 + n15] = (_Float16)p1[r];
        }
        #pragma unroll
        for (int ct = 0; ct < 16; ++ct) {
            #pragma unroll
            for (int r = 0; r < 4; ++r) o[ct][r] *= alpha[r];
        }
        // same-wave cross-lane LDS hazard: drain writes before reading P strip
        asm volatile("s_waitcnt lgkmcnt(0)" ::: "memory");
        const half8 pa = *(const half8*)(pw + n15*P_RS + 8*qq);
        #pragma unroll
        for (int ct = 0; ct < 16; ++ct) {
            const half8 vf = *(const half8*)(vt + (16*ct + n15)*VT_RS + 8*qq);
            o[ct] = __builtin_amdgcn_mfma_f32_16x16x32_f16(pa, vf, o[ct], 0,0,0);
        }
        __syncthreads();
    }

    // ---- epilogue: out[b][d][i] = O[i][d] / (16 * l_i), transposed via LDS
    float osc[4];
    #pragma unroll
    for (int r = 0; r < 4; ++r) osc[r] = 1.0f / (l_r[r] * 16.0f);

    #pragma unroll
    for (int p = 0; p < 4; ++p) {           // 64 d-columns per pass
        #pragma unroll
        for (int c = 0; c < 4; ++c) {
            const int ct = 4*p + c;
            #pragma unroll
            for (int r = 0; r < 4; ++r)
                och[(16*c + n15)*OCH_RS + 16*w + 4*qq + r] = o[ct][r] * osc[r];
        }
        __syncthreads();
        #pragma unroll
        for (int it = 0; it < 4; ++it) {
            const int dl = 16*it + (tid >> 5);
            const int fi = (tid & 31) * 4;
            const float4 vv = *(const float4*)(och + dl*OCH_RS + fi);
            *(float4*)(ob + (size_t)(64*p + dl)*S_ + i0 + fi) = vv;
        }
        __syncthreads();
    }
}

extern "C" void kernel_launch(void* const* d_in, const int* in_sizes, int n_in,
                              void* d_out, int out_size, void* d_ws, size_t ws_size,
                              hipStream_t stream)
{
    const float* q    = (const float*)d_in[0];
    const float* k    = (const float*)d_in[1];
    const float* v    = (const float*)d_in[2];
    const int*   mask = (const int*)d_in[3];
    float*       out  = (float*)d_out;
    attn_flash_f16<<<dim3(B_ * (S_/BM)), dim3(NTHREADS), 0, stream>>>(q, k, v, mask, out);
}